// Round 7
// baseline (411.064 us; speedup 1.0000x reference)
//
#include <hip/hip_runtime.h>
#include <math.h>

// LSTM B=8192,T=512,IN=3,H=32,OUT=2 fp32.
// R15: dual-stream software pipeline, 1 wave/SIMD.
// Invariant (R8-R14): per-SIMD issue work is conserved under every tiling
// (28 trans wave-instr + 12 MFMA + packed arith per SIMD-step); only packing
// efficiency and idle vary. R13 (best, 272us): packed 750 + MFMA 209 + idle
// 314 cyc/step -- 2 staggered waves/SIMD can't reliably cover the serial
// chain (bar -> ds_read 120 -> MFMA dep-3 -> trans chain ~200).
// Fix: ILP instead of TLP. Each 4-wave block carries TWO independent
// 16-batch sets (A,B) phase-offset by half a step:
//   [readBfragB || MFMA_A || xpA || gates_A ; write_A ; lgkm-bar]
//   [readBfragA || MFMA_B || xpB || gates_B ; write_B ; lgkm-bar]
// Every ds_read is issued a half-period (~250cy) before its consuming MFMA
// -> LDS latency + MFMA chain hide under the other set's gate chain,
// compiler-statically. Full f32x2 packing kept (each half = R13's code).
// 256 blocks x 256 thr = 1024 waves = 1/SIMD (1 block/CU).
// Barriers are lgkmcnt-only (syncthreads' vmcnt(0) drain would expose HBM
// x-load latency). Single-buffered LDS per set is race-free: reads complete
// before their wave crosses the next barrier (lgkm(0) at every barrier) and
// the overwrite is 2 barriers later.

namespace {
constexpr int   kT   = 512;
constexpr float kL2E = 1.44269504088896340736f;
}

typedef __bf16 bf16x8 __attribute__((ext_vector_type(8)));
typedef float  f32x4  __attribute__((ext_vector_type(4)));
typedef float  f32x2  __attribute__((ext_vector_type(2)));
typedef unsigned int u32x4 __attribute__((ext_vector_type(4)));

union Frag {
    bf16x8 v;
    unsigned short u[8];
    unsigned int   d[4];
    u32x4          q4;
};

__device__ __forceinline__ unsigned short bf_rne(float f) {
    unsigned u = __float_as_uint(f);
    u += 0x7fffu + ((u >> 16) & 1u);
    return (unsigned short)(u >> 16);
}
__device__ __forceinline__ float bf_tof(unsigned short h) {
    return __uint_as_float((unsigned)h << 16);
}
__device__ __forceinline__ float fast_exp2(float v) { return __builtin_amdgcn_exp2f(v); }
__device__ __forceinline__ float fast_rcp(float v)  { return __builtin_amdgcn_rcpf(v); }

// v_cvt_pk_bf16_f32: dst = [lo16 = bf16_rne(a), hi16 = bf16_rne(b)]
__device__ __forceinline__ unsigned cvt_pk_bf16(float a, float b) {
    unsigned r;
    asm("v_cvt_pk_bf16_f32 %0, %1, %2" : "=v"(r) : "v"(a), "v"(b));
    return r;
}

__device__ __forceinline__ f32x2 fma2(f32x2 a, f32x2 b, f32x2 c) {
    return __builtin_elementwise_fma(a, b, c);
}
__device__ __forceinline__ f32x2 exp22(f32x2 v) {
    f32x2 r = {fast_exp2(v.x), fast_exp2(v.y)};
    return r;
}
__device__ __forceinline__ f32x2 rcp2(f32x2 v) {
    f32x2 r = {fast_rcp(v.x), fast_rcp(v.y)};
    return r;
}
__device__ __forceinline__ f32x2 sp2(float v) {
    f32x2 r = {v, v};
    return r;
}

// lgkmcnt-only barrier: ds ops drained, global loads stay in flight.
__device__ __forceinline__ void lgkm_barrier() {
    asm volatile("s_waitcnt lgkmcnt(0)" ::: "memory");
    __builtin_amdgcn_s_barrier();
    asm volatile("" ::: "memory");
}

#define MFMA16 __builtin_amdgcn_mfma_f32_16x16x32_bf16

extern "C" __global__ __launch_bounds__(256, 1)
void lstm_dual(const float* __restrict__ x,
               const float* __restrict__ W_ih,
               const float* __restrict__ W_hh,
               const float* __restrict__ b_ih,
               const float* __restrict__ b_hh,
               const float* __restrict__ W_fc,
               const float* __restrict__ b_fc,
               float* __restrict__ out) {
    const int tid  = threadIdx.x;
    const int lane = tid & 63;
    const int w    = tid >> 6;          // wave id 0..3: owns units 8w..8w+7
    const int n    = lane & 15;         // batch-within-set == B/D column
    const int q    = lane >> 4;         // k-quad / D row group
    const int bid  = blockIdx.x;
    const int bA   = bid * 32 + n;      // set A batch
    const int bB   = bA + 16;           // set B batch

    // single-buffered h planes per set: [set][hi/lo][batch][unit+pad]
    __shared__ __align__(16) unsigned short lds_h[2][2][16][40];
    {   // zero-init (t=0 reads of B(-1)/A(0-pre) must see 0): 1280 dwords
        unsigned* z = (unsigned*)&lds_h[0][0][0][0];
#pragma unroll
        for (int i = 0; i < 5; ++i) z[tid + 256 * i] = 0u;
    }
    __syncthreads();

    // ---- A frags (shared by both sets): chunk c, A row m -> W row
    // R(m) = 32*(m&3) + 8w + 2*(m>>2) + c  (verified R13)
    // => acc_c[r] = gate r of unit u = 8w + 2q + c (adjacent units per lane).
    Frag Ah[2], Al[2];
#pragma unroll
    for (int c = 0; c < 2; ++c) {
        const int   g = n & 3;
        const float s = (g == 2) ? -2.0f * kL2E : -kL2E;
        const int   R = 32 * g + 8 * w + 2 * (n >> 2) + c;
#pragma unroll
        for (int j = 0; j < 8; ++j) {
            const float wv = W_hh[R * 32 + 8 * q + j] * s;
            const unsigned short hb = bf_rne(wv);
            Ah[c].u[j] = hb;
            Al[c].u[j] = bf_rne(wv - bf_tof(hb));
        }
    }

    // ---- x-path constants (shared): units (u0, u0+1) x 4 gates ----
    const int u0 = 8 * w + 2 * q;
    f32x2 xwp[4][3], xbp[4];
#pragma unroll
    for (int g = 0; g < 4; ++g) {
        const float s  = (g == 2) ? -2.0f * kL2E : -kL2E;
        const int   R0 = 32 * g + u0, R1 = R0 + 1;
#pragma unroll
        for (int k = 0; k < 3; ++k) {
            f32x2 wv = {W_ih[R0 * 3 + k] * s, W_ih[R1 * 3 + k] * s};
            xwp[g][k] = wv;
        }
        f32x2 bb = {(b_ih[R0] + b_hh[R0]) * s, (b_ih[R1] + b_hh[R1]) * s};
        xbp[g] = bb;
    }

    const float* xA = x + (size_t)bA * kT * 3;
    const float* xB = x + (size_t)bB * kT * 3;

    f32x2 cstA = {0.f, 0.f}, cstB = {0.f, 0.f};
    Frag BhA, BlA, BhB, BlB;
#pragma unroll
    for (int j = 0; j < 4; ++j) { BhA.d[j] = 0; BlA.d[j] = 0; BhB.d[j] = 0; BlB.d[j] = 0; }

    // prologue: xp(0) for both sets; held x(1)
    f32x4 xpA0, xpA1, xpB0, xpB1;
    {
        const float a0 = xA[0], a1 = xA[1], a2 = xA[2];
        const float b0 = xB[0], b1 = xB[1], b2 = xB[2];
#pragma unroll
        for (int g = 0; g < 4; ++g) {
            f32x2 pA = fma2(sp2(a0), xwp[g][0],
                       fma2(sp2(a1), xwp[g][1],
                       fma2(sp2(a2), xwp[g][2], xbp[g])));
            f32x2 pB = fma2(sp2(b0), xwp[g][0],
                       fma2(sp2(b1), xwp[g][1],
                       fma2(sp2(b2), xwp[g][2], xbp[g])));
            xpA0[g] = pA.x; xpA1[g] = pA.y;
            xpB0[g] = pB.x; xpB1[g] = pB.y;
        }
    }
    float hA0 = xA[3], hA1 = xA[4], hA2 = xA[5];   // held x(1), set A
    float hB0 = xB[3], hB1 = xB[4], hB2 = xB[5];   // held x(1), set B

    // gate math (R13-identical, f32x2 over adjacent units)
    auto gates = [&](const f32x4& g0, const f32x4& g1, f32x2& cst) -> f32x2 {
        const f32x2 one = {1.f, 1.f};
        f32x2 P0 = {g0[0], g1[0]};
        f32x2 P1 = {g0[1], g1[1]};
        f32x2 P2 = {g0[2], g1[2]};
        f32x2 P3 = {g0[3], g1[3]};
        f32x2 Ei = exp22(P0);
        f32x2 Ef = exp22(P1);
        f32x2 Eg = exp22(P2);
        f32x2 Eo = exp22(P3);
        f32x2 pf  = one + Ef;
        f32x2 pi  = one + Ei;
        f32x2 pg  = one + Eg;
        f32x2 tig = pi * pg;
        f32x2 den = tig * pf;
        f32x2 num = fma2(cst, tig, (one - Eg) * pf);
        f32x2 c   = num * rcp2(den);
        cst = c;
        f32x2 Ec  = exp22(c * sp2(-2.0f * kL2E));
        Ec.x = fminf(Ec.x, 1e30f);
        Ec.y = fminf(Ec.y, 1e30f);
        f32x2 od  = (one + Eo) * (one + Ec);
        return (one - Ec) * rcp2(od);
    };
    auto packwrite = [&](f32x2 h2, int set) {
        const unsigned hh  = cvt_pk_bf16(h2.x, h2.y);
        const float hi0f = __uint_as_float(hh << 16);
        const float hi1f = __uint_as_float(hh & 0xFFFF0000u);
        const unsigned hl  = cvt_pk_bf16(h2.x - hi0f, h2.y - hi1f);
        *(unsigned*)&lds_h[set][0][n][u0] = hh;   // u0 even -> 4B aligned
        *(unsigned*)&lds_h[set][1][n][u0] = hl;
    };

    for (int t = 0; t < kT; ++t) {
        const int tn = (t + 2 < kT) ? t + 2 : kT - 1;

        // ================= half A =================
        // read BfragB(t-1) now; consumed by MFMA_B after the barrier.
        BhB.q4 = *(const u32x4*)&lds_h[1][0][n][8 * q];
        BlB.q4 = *(const u32x4*)&lds_h[1][1][n][8 * q];

        f32x4 a0 = MFMA16(Ah[0].v, BhA.v, xpA0, 0, 0, 0);
        f32x4 a1 = MFMA16(Ah[1].v, BhA.v, xpA1, 0, 0, 0);
        a0 = MFMA16(Al[0].v, BhA.v, a0, 0, 0, 0);
        a1 = MFMA16(Al[1].v, BhA.v, a1, 0, 0, 0);
        a0 = MFMA16(Ah[0].v, BlA.v, a0, 0, 0, 0);
        a1 = MFMA16(Ah[1].v, BlA.v, a1, 0, 0, 0);

        const float nA0 = xA[tn * 3 + 0];
        const float nA1 = xA[tn * 3 + 1];
        const float nA2 = xA[tn * 3 + 2];
#pragma unroll
        for (int g = 0; g < 4; ++g) {
            f32x2 p = fma2(sp2(hA0), xwp[g][0],
                      fma2(sp2(hA1), xwp[g][1],
                      fma2(sp2(hA2), xwp[g][2], xbp[g])));
            xpA0[g] = p.x; xpA1[g] = p.y;
        }

        packwrite(gates(a0, a1, cstA), 0);
        hA0 = nA0; hA1 = nA1; hA2 = nA2;

        lgkm_barrier();

        // ================= half B =================
        // read BfragA(t) now; consumed by MFMA_A after the barrier.
        BhA.q4 = *(const u32x4*)&lds_h[0][0][n][8 * q];
        BlA.q4 = *(const u32x4*)&lds_h[0][1][n][8 * q];

        f32x4 b0 = MFMA16(Ah[0].v, BhB.v, xpB0, 0, 0, 0);
        f32x4 b1 = MFMA16(Ah[1].v, BhB.v, xpB1, 0, 0, 0);
        b0 = MFMA16(Al[0].v, BhB.v, b0, 0, 0, 0);
        b1 = MFMA16(Al[1].v, BhB.v, b1, 0, 0, 0);
        b0 = MFMA16(Ah[0].v, BlB.v, b0, 0, 0, 0);
        b1 = MFMA16(Ah[1].v, BlB.v, b1, 0, 0, 0);

        const float nB0 = xB[tn * 3 + 0];
        const float nB1 = xB[tn * 3 + 1];
        const float nB2 = xB[tn * 3 + 2];
#pragma unroll
        for (int g = 0; g < 4; ++g) {
            f32x2 p = fma2(sp2(hB0), xwp[g][0],
                      fma2(sp2(hB1), xwp[g][1],
                      fma2(sp2(hB2), xwp[g][2], xbp[g])));
            xpB0[g] = p.x; xpB1[g] = p.y;
        }

        packwrite(gates(b0, b1, cstB), 1);
        hB0 = nB0; hB1 = nB1; hB2 = nB2;

        lgkm_barrier();
    }

    // ---- epilogue: wave 0 -> set A, wave 1 -> set B ----
    if (w < 2) {
        const int set = w;
        const int bb  = bid * 32 + set * 16 + n;
        Frag Hh, Hl;
        Hh.q4 = *(const u32x4*)&lds_h[set][0][n][8 * q];
        Hl.q4 = *(const u32x4*)&lds_h[set][1][n][8 * q];
        float s0 = 0.f, s1 = 0.f;
#pragma unroll
        for (int j = 0; j < 8; ++j) {
            const float hv = bf_tof(Hh.u[j]) + bf_tof(Hl.u[j]);
            const int   u  = 8 * q + j;
            s0 = fmaf(hv, W_fc[u], s0);
            s1 = fmaf(hv, W_fc[32 + u], s1);
        }
        s0 += __shfl_xor(s0, 16, 64); s1 += __shfl_xor(s1, 16, 64);
        s0 += __shfl_xor(s0, 32, 64); s1 += __shfl_xor(s1, 32, 64);
        if (lane < 16) {
            out[(size_t)bb * 2 + 0] = s0 + b_fc[0];
            out[(size_t)bb * 2 + 1] = s1 + b_fc[1];
        }
    }
}

extern "C" void kernel_launch(void* const* d_in, const int* in_sizes, int n_in,
                              void* d_out, int out_size, void* d_ws, size_t ws_size,
                              hipStream_t stream) {
    const float* x    = (const float*)d_in[0];
    const float* W_ih = (const float*)d_in[1];
    const float* W_hh = (const float*)d_in[2];
    const float* b_ih = (const float*)d_in[3];
    const float* b_hh = (const float*)d_in[4];
    const float* W_fc = (const float*)d_in[5];
    const float* b_fc = (const float*)d_in[6];
    float* out = (float*)d_out;

    const int batch = in_sizes[0] / (kT * 3);   // 8192
    dim3 grid(batch / 32);                      // 256 blocks of 4 waves
    dim3 block(256);                            // -> 1 block/CU, 1 wave/SIMD
    hipLaunchKernelGGL(lstm_dual, grid, block, 0, stream,
                       x, W_ih, W_hh, b_ih, b_hh, W_fc, b_fc, out);
}

// Round 8
// 385.248 us; speedup vs baseline: 1.0670x; 1.0670x over previous
//
#include <hip/hip_runtime.h>
#include <math.h>

// LSTM B=8192,T=512,IN=3,H=32,OUT=2 fp32.
// R16: dual-stream CRISS-CROSS pipeline, 1 wave/SIMD.
// R15 failed (374us, 44% idle) because gates_X consumed MFMA_X of the SAME
// half: issue MFMA -> stall on chain -> serial trans chain -> barrier, with
// nothing independent in flight at 1 wave/SIMD.
// R16 rotates the schedule so every long-latency edge crosses independent
// work:   halfE(t): read BfragA(t-1) | gates_B(t-1) (acc from last half) |
//                   write h_B | MFMA_A(t) (frag read ~200cy ago) | xpA | bar
//         halfO(t): same with A<->B.
// ds_read hidden under gates; MFMA results age a half before their gates;
// all compiler-static. Streams A,B = 2 independent 16-batch sets per block.
// 256 blocks x 256 thr = 1024 waves = 1/SIMD. lgkm-only barriers (x loads
// stay in flight). Single-buffer LDS per stream is race-free: reads drained
// at the barrier, overwrite is 2 halves later. Zero-frag first steps become
// acc = xp (D = A*0 + C), so no LDS zero-init.
// Per-wave per half: 6 MFMA + 14 trans + ~40 VALU (f32x2 packing kept).

namespace {
constexpr int   kT   = 512;
constexpr float kL2E = 1.44269504088896340736f;
}

typedef __bf16 bf16x8 __attribute__((ext_vector_type(8)));
typedef float  f32x4  __attribute__((ext_vector_type(4)));
typedef float  f32x2  __attribute__((ext_vector_type(2)));
typedef unsigned int u32x4 __attribute__((ext_vector_type(4)));

union Frag {
    bf16x8 v;
    unsigned short u[8];
    unsigned int   d[4];
    u32x4          q4;
};

__device__ __forceinline__ unsigned short bf_rne(float f) {
    unsigned u = __float_as_uint(f);
    u += 0x7fffu + ((u >> 16) & 1u);
    return (unsigned short)(u >> 16);
}
__device__ __forceinline__ float bf_tof(unsigned short h) {
    return __uint_as_float((unsigned)h << 16);
}
__device__ __forceinline__ float fast_exp2(float v) { return __builtin_amdgcn_exp2f(v); }
__device__ __forceinline__ float fast_rcp(float v)  { return __builtin_amdgcn_rcpf(v); }

// v_cvt_pk_bf16_f32: dst = [lo16 = bf16_rne(a), hi16 = bf16_rne(b)]
__device__ __forceinline__ unsigned cvt_pk_bf16(float a, float b) {
    unsigned r;
    asm("v_cvt_pk_bf16_f32 %0, %1, %2" : "=v"(r) : "v"(a), "v"(b));
    return r;
}

__device__ __forceinline__ f32x2 fma2(f32x2 a, f32x2 b, f32x2 c) {
    return __builtin_elementwise_fma(a, b, c);
}
__device__ __forceinline__ f32x2 exp22(f32x2 v) {
    f32x2 r = {fast_exp2(v.x), fast_exp2(v.y)};
    return r;
}
__device__ __forceinline__ f32x2 rcp2(f32x2 v) {
    f32x2 r = {fast_rcp(v.x), fast_rcp(v.y)};
    return r;
}
__device__ __forceinline__ f32x2 sp2(float v) {
    f32x2 r = {v, v};
    return r;
}

// lgkmcnt-only barrier: ds ops drained, global loads stay in flight.
__device__ __forceinline__ void lgkm_barrier() {
    asm volatile("s_waitcnt lgkmcnt(0)" ::: "memory");
    __builtin_amdgcn_s_barrier();
    asm volatile("" ::: "memory");
}

#define MFMA16 __builtin_amdgcn_mfma_f32_16x16x32_bf16

extern "C" __global__ __launch_bounds__(256, 1)
void lstm_xx(const float* __restrict__ x,
             const float* __restrict__ W_ih,
             const float* __restrict__ W_hh,
             const float* __restrict__ b_ih,
             const float* __restrict__ b_hh,
             const float* __restrict__ W_fc,
             const float* __restrict__ b_fc,
             float* __restrict__ out) {
    const int tid  = threadIdx.x;
    const int lane = tid & 63;
    const int w    = tid >> 6;          // wave id 0..3: owns units 8w..8w+7
    const int n    = lane & 15;         // batch-within-set == B/D column
    const int q    = lane >> 4;         // k-quad / D row group
    const int bid  = blockIdx.x;
    const int bA   = bid * 32 + n;      // set A batch
    const int bB   = bA + 16;           // set B batch

    // single-buffered h planes per set: [set][hi/lo][batch][unit+pad]
    __shared__ __align__(16) unsigned short lds_h[2][2][16][40];

    // ---- A frags (shared by both sets): chunk c, A row m -> W row
    // R(m) = 32*(m&3) + 8w + 2*(m>>2) + c  (verified R13)
    // => acc_c[r] = gate r of unit u = 8w + 2q + c (adjacent units per lane).
    Frag Ah[2], Al[2];
#pragma unroll
    for (int c = 0; c < 2; ++c) {
        const int   g = n & 3;
        const float s = (g == 2) ? -2.0f * kL2E : -kL2E;
        const int   R = 32 * g + 8 * w + 2 * (n >> 2) + c;
#pragma unroll
        for (int j = 0; j < 8; ++j) {
            const float wv = W_hh[R * 32 + 8 * q + j] * s;
            const unsigned short hb = bf_rne(wv);
            Ah[c].u[j] = hb;
            Al[c].u[j] = bf_rne(wv - bf_tof(hb));
        }
    }

    // ---- x-path constants (shared): units (u0, u0+1) x 4 gates ----
    const int u0 = 8 * w + 2 * q;
    f32x2 xwp[4][3], xbp[4];
#pragma unroll
    for (int g = 0; g < 4; ++g) {
        const float s  = (g == 2) ? -2.0f * kL2E : -kL2E;
        const int   R0 = 32 * g + u0, R1 = R0 + 1;
#pragma unroll
        for (int k = 0; k < 3; ++k) {
            f32x2 wv = {W_ih[R0 * 3 + k] * s, W_ih[R1 * 3 + k] * s};
            xwp[g][k] = wv;
        }
        f32x2 bb = {(b_ih[R0] + b_hh[R0]) * s, (b_ih[R1] + b_hh[R1]) * s};
        xbp[g] = bb;
    }

    const float* xA = x + (size_t)bA * kT * 3;
    const float* xB = x + (size_t)bB * kT * 3;

    f32x2 cstA = {0.f, 0.f}, cstB = {0.f, 0.f};
    Frag BhA, BlA, BhB, BlB;

    // gate math (R13-identical, f32x2 over adjacent units)
    auto gates = [&](const f32x4& g0, const f32x4& g1, f32x2& cst) -> f32x2 {
        const f32x2 one = {1.f, 1.f};
        f32x2 P0 = {g0[0], g1[0]};
        f32x2 P1 = {g0[1], g1[1]};
        f32x2 P2 = {g0[2], g1[2]};
        f32x2 P3 = {g0[3], g1[3]};
        f32x2 Ei = exp22(P0);
        f32x2 Ef = exp22(P1);
        f32x2 Eg = exp22(P2);
        f32x2 Eo = exp22(P3);
        f32x2 pf  = one + Ef;
        f32x2 pi  = one + Ei;
        f32x2 pg  = one + Eg;
        f32x2 tig = pi * pg;
        f32x2 den = tig * pf;
        f32x2 num = fma2(cst, tig, (one - Eg) * pf);
        f32x2 c   = num * rcp2(den);
        cst = c;
        f32x2 Ec  = exp22(c * sp2(-2.0f * kL2E));
        Ec.x = fminf(Ec.x, 1e30f);
        Ec.y = fminf(Ec.y, 1e30f);
        f32x2 od  = (one + Eo) * (one + Ec);
        return (one - Ec) * rcp2(od);
    };
    auto packwrite = [&](f32x2 h2, int set) {
        const unsigned hh  = cvt_pk_bf16(h2.x, h2.y);
        const float hi0f = __uint_as_float(hh << 16);
        const float hi1f = __uint_as_float(hh & 0xFFFF0000u);
        const unsigned hl  = cvt_pk_bf16(h2.x - hi0f, h2.y - hi1f);
        *(unsigned*)&lds_h[set][0][n][u0] = hh;   // u0 even -> 4B aligned
        *(unsigned*)&lds_h[set][1][n][u0] = hl;
    };

    // ---- prologue ----
    f32x4 xpA0, xpA1, xpB0, xpB1;
    {
        const float a0 = xA[0], a1 = xA[1], a2 = xA[2];
        const float b0 = xB[0], b1 = xB[1], b2 = xB[2];
#pragma unroll
        for (int g = 0; g < 4; ++g) {
            f32x2 pA = fma2(sp2(a0), xwp[g][0],
                       fma2(sp2(a1), xwp[g][1],
                       fma2(sp2(a2), xwp[g][2], xbp[g])));
            f32x2 pB = fma2(sp2(b0), xwp[g][0],
                       fma2(sp2(b1), xwp[g][1],
                       fma2(sp2(b2), xwp[g][2], xbp[g])));
            xpA0[g] = pA.x; xpA1[g] = pA.y;
            xpB0[g] = pB.x; xpB1[g] = pB.y;
        }
    }
    float hA0 = xA[3], hA1 = xA[4], hA2 = xA[5];   // held x(1), set A
    float hB0 = xB[3], hB1 = xB[4], hB2 = xB[5];   // held x(1), set B

    // half0 (t=0, stream A): h_A(-1)=0 => acc_A(0) = xp_A(0) (D = A*0 + C).
    f32x4 accA0 = xpA0, accA1 = xpA1;
    {   // xpA <- xp_A(1); heldA <- x_A(2)
        const float n0 = xA[6], n1 = xA[7], n2 = xA[8];
#pragma unroll
        for (int g = 0; g < 4; ++g) {
            f32x2 p = fma2(sp2(hA0), xwp[g][0],
                      fma2(sp2(hA1), xwp[g][1],
                      fma2(sp2(hA2), xwp[g][2], xbp[g])));
            xpA0[g] = p.x; xpA1[g] = p.y;
        }
        hA0 = n0; hA1 = n1; hA2 = n2;
    }

    // half1 (stream B t=0, gates_A(0)): h_B(-1)=0 => acc_B(0) = xp_B(0).
    f32x4 accB0 = xpB0, accB1 = xpB1;
    packwrite(gates(accA0, accA1, cstA), 0);       // h_A(0) -> LDS
    {   // xpB <- xp_B(1); heldB <- x_B(2)
        const float n0 = xB[6], n1 = xB[7], n2 = xB[8];
#pragma unroll
        for (int g = 0; g < 4; ++g) {
            f32x2 p = fma2(sp2(hB0), xwp[g][0],
                      fma2(sp2(hB1), xwp[g][1],
                      fma2(sp2(hB2), xwp[g][2], xbp[g])));
            xpB0[g] = p.x; xpB1[g] = p.y;
        }
        hB0 = n0; hB1 = n1; hB2 = n2;
    }
    lgkm_barrier();

    // ---- main loop: t = 1..511 ----
    for (int t = 1; t < kT; ++t) {
        const int tn = (t + 2 < kT) ? t + 2 : kT - 1;

        // ===== halfE: read BfragA(t-1) | gates_B(t-1) | MFMA_A(t) =====
        BhA.q4 = *(const u32x4*)&lds_h[0][0][n][8 * q];
        BlA.q4 = *(const u32x4*)&lds_h[0][1][n][8 * q];

        packwrite(gates(accB0, accB1, cstB), 1);   // h_B(t-1) -> LDS

        accA0 = MFMA16(Ah[0].v, BhA.v, xpA0, 0, 0, 0);
        accA1 = MFMA16(Ah[1].v, BhA.v, xpA1, 0, 0, 0);
        accA0 = MFMA16(Al[0].v, BhA.v, accA0, 0, 0, 0);
        accA1 = MFMA16(Al[1].v, BhA.v, accA1, 0, 0, 0);
        accA0 = MFMA16(Ah[0].v, BlA.v, accA0, 0, 0, 0);
        accA1 = MFMA16(Ah[1].v, BlA.v, accA1, 0, 0, 0);

        {   // xpA <- xp_A(t+1); heldA <- x_A(t+2)
            const float n0 = xA[tn * 3 + 0];
            const float n1 = xA[tn * 3 + 1];
            const float n2 = xA[tn * 3 + 2];
#pragma unroll
            for (int g = 0; g < 4; ++g) {
                f32x2 p = fma2(sp2(hA0), xwp[g][0],
                          fma2(sp2(hA1), xwp[g][1],
                          fma2(sp2(hA2), xwp[g][2], xbp[g])));
                xpA0[g] = p.x; xpA1[g] = p.y;
            }
            hA0 = n0; hA1 = n1; hA2 = n2;
        }
        lgkm_barrier();

        // ===== halfO: read BfragB(t-1) | gates_A(t) | MFMA_B(t) =====
        BhB.q4 = *(const u32x4*)&lds_h[1][0][n][8 * q];
        BlB.q4 = *(const u32x4*)&lds_h[1][1][n][8 * q];

        packwrite(gates(accA0, accA1, cstA), 0);   // h_A(t) -> LDS

        accB0 = MFMA16(Ah[0].v, BhB.v, xpB0, 0, 0, 0);
        accB1 = MFMA16(Ah[1].v, BhB.v, xpB1, 0, 0, 0);
        accB0 = MFMA16(Al[0].v, BhB.v, accB0, 0, 0, 0);
        accB1 = MFMA16(Al[1].v, BhB.v, accB1, 0, 0, 0);
        accB0 = MFMA16(Ah[0].v, BlB.v, accB0, 0, 0, 0);
        accB1 = MFMA16(Ah[1].v, BlB.v, accB1, 0, 0, 0);

        {   // xpB <- xp_B(t+1); heldB <- x_B(t+2)
            const float n0 = xB[tn * 3 + 0];
            const float n1 = xB[tn * 3 + 1];
            const float n2 = xB[tn * 3 + 2];
#pragma unroll
            for (int g = 0; g < 4; ++g) {
                f32x2 p = fma2(sp2(hB0), xwp[g][0],
                          fma2(sp2(hB1), xwp[g][1],
                          fma2(sp2(hB2), xwp[g][2], xbp[g])));
                xpB0[g] = p.x; xpB1[g] = p.y;
            }
            hB0 = n0; hB1 = n1; hB2 = n2;
        }
        lgkm_barrier();
    }

    // ---- tail: gates_B(511) -> h_B(511) ----
    packwrite(gates(accB0, accB1, cstB), 1);
    lgkm_barrier();

    // ---- epilogue: wave 0 -> set A, wave 1 -> set B ----
    if (w < 2) {
        const int set = w;
        const int bb  = bid * 32 + set * 16 + n;
        Frag Hh, Hl;
        Hh.q4 = *(const u32x4*)&lds_h[set][0][n][8 * q];
        Hl.q4 = *(const u32x4*)&lds_h[set][1][n][8 * q];
        float s0 = 0.f, s1 = 0.f;
#pragma unroll
        for (int j = 0; j < 8; ++j) {
            const float hv = bf_tof(Hh.u[j]) + bf_tof(Hl.u[j]);
            const int   u  = 8 * q + j;
            s0 = fmaf(hv, W_fc[u], s0);
            s1 = fmaf(hv, W_fc[32 + u], s1);
        }
        s0 += __shfl_xor(s0, 16, 64); s1 += __shfl_xor(s1, 16, 64);
        s0 += __shfl_xor(s0, 32, 64); s1 += __shfl_xor(s1, 32, 64);
        if (lane < 16) {
            out[(size_t)bb * 2 + 0] = s0 + b_fc[0];
            out[(size_t)bb * 2 + 1] = s1 + b_fc[1];
        }
    }
}

extern "C" void kernel_launch(void* const* d_in, const int* in_sizes, int n_in,
                              void* d_out, int out_size, void* d_ws, size_t ws_size,
                              hipStream_t stream) {
    const float* x    = (const float*)d_in[0];
    const float* W_ih = (const float*)d_in[1];
    const float* W_hh = (const float*)d_in[2];
    const float* b_ih = (const float*)d_in[3];
    const float* b_hh = (const float*)d_in[4];
    const float* W_fc = (const float*)d_in[5];
    const float* b_fc = (const float*)d_in[6];
    float* out = (float*)d_out;

    const int batch = in_sizes[0] / (kT * 3);   // 8192
    dim3 grid(batch / 32);                      // 256 blocks of 4 waves
    dim3 block(256);                            // -> 1 block/CU, 1 wave/SIMD
    hipLaunchKernelGGL(lstm_xx, grid, block, 0, stream,
                       x, W_ih, W_hh, b_ih, b_hh, W_fc, b_fc, out);
}